// Round 1
// baseline (936.730 us; speedup 1.0000x reference)
//
#include <hip/hip_runtime.h>

#define NV 3
#define NN 20000
#define NTT 60000
#define NE 800000
#define NR 6
#define NB 4
#define DD 128
#define INF 2000
#define NL 5
#define LDT 40  // padded LDS k-stride (32 + 8 bf16)

typedef __attribute__((ext_vector_type(8))) short short8;
typedef __attribute__((ext_vector_type(4))) float f32x4;

__device__ __forceinline__ unsigned short f2bf(float f) {
    unsigned int u = __float_as_uint(f);
    u += 0x7FFFu + ((u >> 16) & 1u);   // RNE
    return (unsigned short)(u >> 16);
}
__device__ __forceinline__ float bf2f(unsigned short h) {
    return __uint_as_float(((unsigned int)h) << 16);
}

// ---------- prep kernels ----------

// wT[v][n][k] = bf16(w_proj_v[k][n])
__global__ void prep_wT(const float* __restrict__ w0, const float* __restrict__ w1,
                        const float* __restrict__ w2, unsigned short* __restrict__ wT) {
    int idx = blockIdx.x * 256 + threadIdx.x;
    if (idx >= NV * DD * INF) return;
    int v = idx / (DD * INF);
    int rem = idx - v * DD * INF;
    int n = rem / INF;
    int k = rem - n * INF;
    const float* w = (v == 0) ? w0 : ((v == 1) ? w1 : w2);
    wT[idx] = f2bf(w[(size_t)k * DD + n]);
}

// wTrel[r][o][d] = bf16( sum_b comp[r][b] * basis[b][d][o] )   (= W_r^T)
__global__ void prep_wrel(const float* __restrict__ basis, const float* __restrict__ comp,
                          unsigned short* __restrict__ wTrel) {
    int idx = blockIdx.x * 256 + threadIdx.x;
    if (idx >= NR * DD * DD) return;
    int r = idx / (DD * DD);
    int rem = idx - r * DD * DD;
    int o = rem / DD;
    int d = rem - o * DD;
    float s = 0.f;
    #pragma unroll
    for (int b = 0; b < NB; b++) s += comp[r * NB + b] * basis[((size_t)b * DD + d) * DD + o];
    wTrel[idx] = f2bf(s);
}

// qvec[r][d] = sum_o W_r[d][o] att_q[o]; same for kvec with att_k
__global__ void prep_qkvec(const float* __restrict__ basis, const float* __restrict__ comp,
                           const float* __restrict__ att_q, const float* __restrict__ att_k,
                           float* __restrict__ qvec, float* __restrict__ kvec) {
    int idx = blockIdx.x * 256 + threadIdx.x;
    if (idx >= 2 * NR * DD) return;
    int sel = idx / (NR * DD);
    int rem = idx - sel * (NR * DD);
    int r = rem / DD;
    int d = rem - r * DD;
    const float* att = sel ? att_k : att_q;
    float s = 0.f;
    #pragma unroll
    for (int b = 0; b < NB; b++) {
        float cb = comp[r * NB + b];
        float t = 0.f;
        for (int o = 0; o < DD; o++) t += basis[((size_t)b * DD + d) * DD + o] * att[o];
        s += cb * t;
    }
    (sel ? kvec : qvec)[r * DD + d] = s;
}

__global__ void zero2(int* __restrict__ a, int* __restrict__ b) {
    int i = blockIdx.x * 256 + threadIdx.x;
    if (i < NTT) { a[i] = 0; b[i] = 0; }
}

// ---------- projection GEMM: h = relu(x_v @ W_v + b_v), bf16 out ----------
__global__ __launch_bounds__(256) void proj_gemm(
    const float* __restrict__ x0, const float* __restrict__ x1, const float* __restrict__ x2,
    const float* __restrict__ b0, const float* __restrict__ b1, const float* __restrict__ b2,
    const unsigned short* __restrict__ wT, unsigned short* __restrict__ hout) {
    __shared__ unsigned short lds_a[128 * LDT];
    __shared__ unsigned short lds_b[128 * LDT];
    int v = blockIdx.y;
    const float* x = (v == 0) ? x0 : ((v == 1) ? x1 : x2);
    const float* bias = (v == 0) ? b0 : ((v == 1) ? b1 : b2);
    const unsigned short* wTv = wT + (size_t)v * DD * INF;

    int t = threadIdx.x;
    int sr = t >> 1, sh = t & 1;
    int gr = blockIdx.x * 128 + sr;
    int lane = t & 63, wid = t >> 6;
    int wm = wid >> 1, wn = wid & 1;
    int lm = lane & 15, lq = lane >> 4;

    f32x4 acc[4][4];
    #pragma unroll
    for (int i = 0; i < 4; i++)
        #pragma unroll
        for (int j = 0; j < 4; j++) {
            acc[i][j][0] = 0.f; acc[i][j][1] = 0.f; acc[i][j][2] = 0.f; acc[i][j][3] = 0.f;
        }

    const int KT = (INF + 31) / 32;  // 63, last one partial (16 valid)
    for (int kk = 0; kk < KT; kk++) {
        int k0 = kk * 32 + sh * 16;
        // A tile: 128 rows x 32 k, fp32 -> bf16
        if (kk < KT - 1 && gr < NN) {
            const float4* src = (const float4*)(x + (size_t)gr * INF + k0);
            #pragma unroll
            for (int j = 0; j < 4; j++) {
                float4 f = src[j];
                ushort4 u;
                u.x = f2bf(f.x); u.y = f2bf(f.y); u.z = f2bf(f.z); u.w = f2bf(f.w);
                *(ushort4*)&lds_a[sr * LDT + sh * 16 + j * 4] = u;
            }
        } else {
            for (int j = 0; j < 16; j++) {
                int k = k0 + j;
                float f = (gr < NN && k < INF) ? x[(size_t)gr * INF + k] : 0.f;
                lds_a[sr * LDT + sh * 16 + j] = f2bf(f);
            }
        }
        // B tile: 128 n x 32 k (already bf16, k-contiguous)
        if (kk < KT - 1) {
            const uint4* src = (const uint4*)(wTv + (size_t)sr * INF + k0);
            *(uint4*)&lds_b[sr * LDT + sh * 16] = src[0];
            *(uint4*)&lds_b[sr * LDT + sh * 16 + 8] = src[1];
        } else {
            for (int j = 0; j < 16; j++) {
                int k = k0 + j;
                lds_b[sr * LDT + sh * 16 + j] = (k < INF) ? wTv[(size_t)sr * INF + k] : (unsigned short)0;
            }
        }
        __syncthreads();
        short8 af[4], bfr[4];
        #pragma unroll
        for (int i = 0; i < 4; i++)
            af[i] = *(const short8*)&lds_a[(wm * 64 + i * 16 + lm) * LDT + lq * 8];
        #pragma unroll
        for (int j = 0; j < 4; j++)
            bfr[j] = *(const short8*)&lds_b[(wn * 64 + j * 16 + lm) * LDT + lq * 8];
        #pragma unroll
        for (int i = 0; i < 4; i++)
            #pragma unroll
            for (int j = 0; j < 4; j++)
                acc[i][j] = __builtin_amdgcn_mfma_f32_16x16x32_bf16(af[i], bfr[j], acc[i][j], 0, 0, 0);
        __syncthreads();
    }
    // epilogue: C row=(lane>>4)*4+reg, col=lane&15  [m89-verified layout]
    #pragma unroll
    for (int i = 0; i < 4; i++) {
        int lr = wm * 64 + i * 16 + lq * 4;
        #pragma unroll
        for (int j = 0; j < 4; j++) {
            int c = wn * 64 + j * 16 + lm;
            float bv = bias[c];
            #pragma unroll
            for (int u = 0; u < 4; u++) {
                int grow = blockIdx.x * 128 + lr + u;
                if (grow < NN) {
                    float o = acc[i][j][u] + bv;
                    o = fmaxf(o, 0.f);
                    hout[((size_t)(v * NN + grow)) * DD + c] = f2bf(o);
                }
            }
        }
    }
}

// ---------- xw GEMM: xw[r] = h @ W_r  (bf16 in, bf16 out, K=128) ----------
__global__ __launch_bounds__(256) void xw_gemm(
    const unsigned short* __restrict__ h, const unsigned short* __restrict__ wTrel,
    unsigned short* __restrict__ xw) {
    __shared__ unsigned short lds_a[128 * LDT];
    __shared__ unsigned short lds_b[128 * LDT];
    int r = blockIdx.y;
    const unsigned short* wTr = wTrel + (size_t)r * DD * DD;
    int t = threadIdx.x;
    int sr = t >> 1, sh = t & 1;
    int grow = blockIdx.x * 128 + sr;
    int grc = (grow < NTT) ? grow : (NTT - 1);  // clamp; epilogue guards
    int lane = t & 63, wid = t >> 6;
    int wm = wid >> 1, wn = wid & 1;
    int lm = lane & 15, lq = lane >> 4;

    f32x4 acc[4][4];
    #pragma unroll
    for (int i = 0; i < 4; i++)
        #pragma unroll
        for (int j = 0; j < 4; j++) {
            acc[i][j][0] = 0.f; acc[i][j][1] = 0.f; acc[i][j][2] = 0.f; acc[i][j][3] = 0.f;
        }

    #pragma unroll
    for (int kk = 0; kk < 4; kk++) {
        int k0 = kk * 32 + sh * 16;
        const uint4* asrc = (const uint4*)(h + (size_t)grc * DD + k0);
        *(uint4*)&lds_a[sr * LDT + sh * 16] = asrc[0];
        *(uint4*)&lds_a[sr * LDT + sh * 16 + 8] = asrc[1];
        const uint4* bsrc = (const uint4*)(wTr + (size_t)sr * DD + k0);
        *(uint4*)&lds_b[sr * LDT + sh * 16] = bsrc[0];
        *(uint4*)&lds_b[sr * LDT + sh * 16 + 8] = bsrc[1];
        __syncthreads();
        short8 af[4], bfr[4];
        #pragma unroll
        for (int i = 0; i < 4; i++)
            af[i] = *(const short8*)&lds_a[(wm * 64 + i * 16 + lm) * LDT + lq * 8];
        #pragma unroll
        for (int j = 0; j < 4; j++)
            bfr[j] = *(const short8*)&lds_b[(wn * 64 + j * 16 + lm) * LDT + lq * 8];
        #pragma unroll
        for (int i = 0; i < 4; i++)
            #pragma unroll
            for (int j = 0; j < 4; j++)
                acc[i][j] = __builtin_amdgcn_mfma_f32_16x16x32_bf16(af[i], bfr[j], acc[i][j], 0, 0, 0);
        __syncthreads();
    }
    #pragma unroll
    for (int i = 0; i < 4; i++) {
        int lr = wm * 64 + i * 16 + lq * 4;
        #pragma unroll
        for (int j = 0; j < 4; j++) {
            int c = wn * 64 + j * 16 + lm;
            #pragma unroll
            for (int u = 0; u < 4; u++) {
                int g2 = blockIdx.x * 128 + lr + u;
                if (g2 < NTT)
                    xw[((size_t)r * NTT + g2) * DD + c] = f2bf(acc[i][j][u]);
            }
        }
    }
}

// ---------- per-(relation,node) attention scalars ----------
__global__ void qk_nodes(const unsigned short* __restrict__ h, const float* __restrict__ qvec,
                         const float* __restrict__ kvec, float* __restrict__ qn,
                         float* __restrict__ kn) {
    int wid = threadIdx.x >> 6, lane = threadIdx.x & 63;
    int node = blockIdx.x * 4 + wid;
    if (node >= NTT) return;
    unsigned int u = *(const unsigned int*)(h + (size_t)node * DD + lane * 2);
    float h0 = bf2f(u & 0xffff), h1 = bf2f(u >> 16);
    #pragma unroll
    for (int r = 0; r < NR; r++) {
        float pq = h0 * qvec[r * DD + lane * 2] + h1 * qvec[r * DD + lane * 2 + 1];
        float pk = h0 * kvec[r * DD + lane * 2] + h1 * kvec[r * DD + lane * 2 + 1];
        #pragma unroll
        for (int off = 32; off; off >>= 1) {
            pq += __shfl_xor(pq, off);
            pk += __shfl_xor(pk, off);
        }
        if (lane == 0) {
            qn[r * NTT + node] = pq;
            kn[r * NTT + node] = pk;
        }
    }
}

// ---------- CSR build ----------
__global__ void hist(const int* __restrict__ dst, int* __restrict__ indeg) {
    int e = blockIdx.x * 256 + threadIdx.x;
    if (e < NE) atomicAdd(&indeg[dst[e]], 1);
}

__global__ __launch_bounds__(1024) void scan_indeg(const int* __restrict__ indeg,
                                                   int* __restrict__ start) {
    int t = threadIdx.x;
    const int per = (NTT + 1023) / 1024;  // 59
    int base = t * per;
    int s = 0;
    for (int i = 0; i < per; i++) {
        int idx = base + i;
        if (idx < NTT) s += indeg[idx];
    }
    int lane = t & 63, wid = t >> 6;
    __shared__ int wsum[16];
    int v = s;
    #pragma unroll
    for (int off = 1; off < 64; off <<= 1) {
        int u = __shfl_up(v, off);
        if (lane >= off) v += u;
    }
    if (lane == 63) wsum[wid] = v;
    __syncthreads();
    if (t < 16) {
        int w = wsum[t];
        #pragma unroll
        for (int off = 1; off < 16; off <<= 1) {
            int u = __shfl_up(w, off);
            if (t >= off) w += u;
        }
        wsum[t] = w;
    }
    __syncthreads();
    int excl = (v - s) + (wid ? wsum[wid - 1] : 0);
    int run = excl;
    for (int i = 0; i < per; i++) {
        int idx = base + i;
        if (idx < NTT) {
            start[idx] = run;
            run += indeg[idx];
        }
    }
    if (t == 1023) start[NTT] = run;
}

__global__ void scatter(const int* __restrict__ dst, const int* __restrict__ start,
                        int* __restrict__ cursor, int* __restrict__ elist) {
    int e = blockIdx.x * 256 + threadIdx.x;
    if (e < NE) {
        int d = dst[e];
        int pos = atomicAdd(&cursor[d], 1);
        elist[start[d] + pos] = e;
    }
}

// ---------- aggregation: one wave per dst node ----------
__global__ void aggregate(const int* __restrict__ elist, const int* __restrict__ start,
                          const int* __restrict__ etype, const int* __restrict__ esrc,
                          const float* __restrict__ qn, const float* __restrict__ kn,
                          const unsigned short* __restrict__ xw,
                          const float* __restrict__ conv_bias, float* __restrict__ h2) {
    int wid = threadIdx.x >> 6, lane = threadIdx.x & 63;
    int node = blockIdx.x * 4 + wid;
    if (node >= NTT) return;
    int s0 = start[node], s1 = start[node + 1];
    float a0 = 0.f, a1 = 0.f, denom = 0.f;
    for (int i = s0; i < s1; i++) {
        int e = elist[i];
        int tt = etype[e], ss = esrc[e];
        float al = qn[tt * NTT + node] + kn[tt * NTT + ss];
        al = (al > 0.f) ? al : 0.2f * al;   // leaky_relu, PyG slope
        float w = __expf(al);               // softmax shift-invariance: no segment_max needed
        denom += w;
        unsigned int u = *(const unsigned int*)(xw + ((size_t)tt * NTT + ss) * DD + lane * 2);
        a0 += w * bf2f(u & 0xffff);
        a1 += w * bf2f(u >> 16);
    }
    float rdenom = 1.f / (denom + 1e-16f);
    float o0 = fmaxf(a0 * rdenom + conv_bias[lane * 2], 0.f);
    float o1 = fmaxf(a1 * rdenom + conv_bias[lane * 2 + 1], 0.f);
    float2 o;
    o.x = o0;
    o.y = o1;
    *(float2*)&h2[(size_t)node * DD + lane * 2] = o;
}

// ---------- final linear: one wave per sample node ----------
__global__ void final_linear(const float* __restrict__ h2, const float* __restrict__ w_int,
                             const float* __restrict__ b_int, float* __restrict__ out) {
    int wid = threadIdx.x >> 6, lane = threadIdx.x & 63;
    int node = blockIdx.x * 4 + wid;
    if (node >= NN) return;
    float acc[NL] = {0.f, 0.f, 0.f, 0.f, 0.f};
    for (int j = lane; j < NV * DD; j += 64) {
        int v = j >> 7, d = j & 127;
        float f = h2[((size_t)(v * NN + node)) * DD + d];
        #pragma unroll
        for (int c = 0; c < NL; c++) acc[c] += f * w_int[j * NL + c];
    }
    #pragma unroll
    for (int c = 0; c < NL; c++) {
        float s = acc[c];
        #pragma unroll
        for (int off = 32; off; off >>= 1) s += __shfl_xor(s, off);
        if (lane == 0) out[(size_t)node * NL + c] = s + b_int[c];
    }
}

extern "C" void kernel_launch(void* const* d_in, const int* in_sizes, int n_in, void* d_out,
                              int out_size, void* d_ws, size_t ws_size, hipStream_t stream) {
    (void)in_sizes; (void)n_in; (void)out_size; (void)ws_size;
    const float* x0 = (const float*)d_in[0];
    const float* w0 = (const float*)d_in[1];
    const float* b0 = (const float*)d_in[2];
    const float* x1 = (const float*)d_in[3];
    const float* w1 = (const float*)d_in[4];
    const float* b1 = (const float*)d_in[5];
    const float* x2 = (const float*)d_in[6];
    const float* w2 = (const float*)d_in[7];
    const float* b2 = (const float*)d_in[8];
    const int* esrc = (const int*)d_in[9];
    const int* edst = (const int*)d_in[10];
    const int* etype = (const int*)d_in[11];
    const float* basis = (const float*)d_in[12];
    const float* comp = (const float*)d_in[13];
    const float* att_q = (const float*)d_in[14];
    const float* att_k = (const float*)d_in[15];
    const float* conv_bias = (const float*)d_in[16];
    const float* w_int = (const float*)d_in[17];
    const float* b_int = (const float*)d_in[18];

    char* ws = (char*)d_ws;
    size_t off = 0;
    auto alloc = [&](size_t bytes) -> void* {
        void* p = ws + off;
        off += bytes;
        off = (off + 255) & ~(size_t)255;
        return p;
    };
    unsigned short* h = (unsigned short*)alloc((size_t)NTT * DD * 2);
    unsigned short* xw = (unsigned short*)alloc((size_t)NR * NTT * DD * 2);
    float* qn = (float*)alloc((size_t)NR * NTT * 4);
    float* kn = (float*)alloc((size_t)NR * NTT * 4);
    unsigned short* wT = (unsigned short*)alloc((size_t)NV * DD * INF * 2);
    unsigned short* wTrel = (unsigned short*)alloc((size_t)NR * DD * DD * 2);
    float* qvec = (float*)alloc((size_t)NR * DD * 4);
    float* kvec = (float*)alloc((size_t)NR * DD * 4);
    int* indeg = (int*)alloc((size_t)NTT * 4);
    int* cursor = (int*)alloc((size_t)NTT * 4);
    int* startp = (int*)alloc((size_t)(NTT + 1) * 4);
    int* elist = (int*)alloc((size_t)NE * 4);
    float* h2 = (float*)alloc((size_t)NTT * DD * 4);

    prep_wT<<<(NV * DD * INF + 255) / 256, 256, 0, stream>>>(w0, w1, w2, wT);
    prep_wrel<<<(NR * DD * DD + 255) / 256, 256, 0, stream>>>(basis, comp, wTrel);
    prep_qkvec<<<(2 * NR * DD + 255) / 256, 256, 0, stream>>>(basis, comp, att_q, att_k, qvec, kvec);
    zero2<<<(NTT + 255) / 256, 256, 0, stream>>>(indeg, cursor);

    proj_gemm<<<dim3((NN + 127) / 128, NV), 256, 0, stream>>>(x0, x1, x2, b0, b1, b2, wT, h);
    qk_nodes<<<(NTT + 3) / 4, 256, 0, stream>>>(h, qvec, kvec, qn, kn);
    xw_gemm<<<dim3((NTT + 127) / 128, NR), 256, 0, stream>>>(h, wTrel, xw);

    hist<<<(NE + 255) / 256, 256, 0, stream>>>(edst, indeg);
    scan_indeg<<<1, 1024, 0, stream>>>(indeg, startp);
    scatter<<<(NE + 255) / 256, 256, 0, stream>>>(edst, startp, cursor, elist);

    aggregate<<<(NTT + 3) / 4, 256, 0, stream>>>(elist, startp, etype, esrc, qn, kn, xw,
                                                 conv_bias, h2);
    final_linear<<<(NN + 3) / 4, 256, 0, stream>>>(h2, w_int, b_int, (float*)d_out);
}

// Round 2
// 899.478 us; speedup vs baseline: 1.0414x; 1.0414x over previous
//
#include <hip/hip_runtime.h>

#define NV 3
#define NN 20000
#define NTT 60000
#define NE 800000
#define NR 6
#define NB 4
#define DD 128
#define INF 2000
#define NL 5
#define LDT 40  // padded LDS k-stride in shorts (32 + 8), 80 B = 16B-aligned

typedef __attribute__((ext_vector_type(8))) short short8;
typedef __attribute__((ext_vector_type(4))) float f32x4;

__device__ __forceinline__ unsigned short f2bf(float f) {
    unsigned int u = __float_as_uint(f);
    u += 0x7FFFu + ((u >> 16) & 1u);   // RNE
    return (unsigned short)(u >> 16);
}
__device__ __forceinline__ float bf2f(unsigned short h) {
    return __uint_as_float(((unsigned int)h) << 16);
}

// ---------- prep kernels ----------

// wT[v][n][k] = bf16(w_proj_v[k][n])
__global__ void prep_wT(const float* __restrict__ w0, const float* __restrict__ w1,
                        const float* __restrict__ w2, unsigned short* __restrict__ wT) {
    int idx = blockIdx.x * 256 + threadIdx.x;
    if (idx >= NV * DD * INF) return;
    int v = idx / (DD * INF);
    int rem = idx - v * DD * INF;
    int n = rem / INF;
    int k = rem - n * INF;
    const float* w = (v == 0) ? w0 : ((v == 1) ? w1 : w2);
    wT[idx] = f2bf(w[(size_t)k * DD + n]);
}

// wTrel[r][o][d] = bf16( sum_b comp[r][b] * basis[b][d][o] )   (= W_r^T)
__global__ void prep_wrel(const float* __restrict__ basis, const float* __restrict__ comp,
                          unsigned short* __restrict__ wTrel) {
    int idx = blockIdx.x * 256 + threadIdx.x;
    if (idx >= NR * DD * DD) return;
    int r = idx / (DD * DD);
    int rem = idx - r * DD * DD;
    int o = rem / DD;
    int d = rem - o * DD;
    float s = 0.f;
    #pragma unroll
    for (int b = 0; b < NB; b++) s += comp[r * NB + b] * basis[((size_t)b * DD + d) * DD + o];
    wTrel[idx] = f2bf(s);
}

// qvec[r][d] = sum_o W_r[d][o] att_q[o]; same for kvec with att_k
__global__ void prep_qkvec(const float* __restrict__ basis, const float* __restrict__ comp,
                           const float* __restrict__ att_q, const float* __restrict__ att_k,
                           float* __restrict__ qvec, float* __restrict__ kvec) {
    int idx = blockIdx.x * 256 + threadIdx.x;
    if (idx >= 2 * NR * DD) return;
    int sel = idx / (NR * DD);
    int rem = idx - sel * (NR * DD);
    int r = rem / DD;
    int d = rem - r * DD;
    const float* att = sel ? att_k : att_q;
    float s = 0.f;
    #pragma unroll
    for (int b = 0; b < NB; b++) {
        float cb = comp[r * NB + b];
        float t = 0.f;
        for (int o = 0; o < DD; o++) t += basis[((size_t)b * DD + d) * DD + o] * att[o];
        s += cb * t;
    }
    (sel ? kvec : qvec)[r * DD + d] = s;
}

__global__ void zero2(int* __restrict__ a, int* __restrict__ b) {
    int i = blockIdx.x * 256 + threadIdx.x;
    if (i < NTT) { a[i] = 0; b[i] = 0; }
}

// ---------- projection GEMM: h = relu(x_v @ W_v + b_v), bf16 out ----------
// 64x128 tile (more blocks -> occupancy), register-double-buffered staging.
__global__ __launch_bounds__(256) void proj_gemm(
    const float* __restrict__ x0, const float* __restrict__ x1, const float* __restrict__ x2,
    const float* __restrict__ b0, const float* __restrict__ b1, const float* __restrict__ b2,
    const unsigned short* __restrict__ wT, unsigned short* __restrict__ hout) {
    __shared__ unsigned short lds_a[64 * LDT];
    __shared__ unsigned short lds_b[128 * LDT];
    int v = blockIdx.y;
    const float* x = (v == 0) ? x0 : ((v == 1) ? x1 : x2);
    const float* bias = (v == 0) ? b0 : ((v == 1) ? b1 : b2);
    const unsigned short* wTv = wT + (size_t)v * DD * INF;

    int t = threadIdx.x;
    // A staging: row = t>>2 (0..63), chunk of 8 fp32 at (t&3)*8
    int arow = t >> 2, aq = t & 3;
    int gr = blockIdx.x * 64 + arow;
    bool arowok = gr < NN;
    // B staging: row = t>>1 (0..127), 16 bf16 at (t&1)*16
    int brow = t >> 1, bh = t & 1;

    int lane = t & 63, wid = t >> 6;
    int wm = wid >> 1, wn = wid & 1;   // wave covers rows wm*32..+31, cols wn*64..+63
    int lm = lane & 15, lq = lane >> 4;

    f32x4 acc[2][4];
    #pragma unroll
    for (int i = 0; i < 2; i++)
        #pragma unroll
        for (int j = 0; j < 4; j++) {
            acc[i][j][0] = 0.f; acc[i][j][1] = 0.f; acc[i][j][2] = 0.f; acc[i][j][3] = 0.f;
        }

    const int KT = (INF + 31) / 32;  // 63 (last partial: 16 valid)
    float4 fa0, fa1;
    uint4 fb0, fb1;

    auto loadA = [&](int kk) {
        int kb = kk * 32 + aq * 8;
        fa0 = make_float4(0.f, 0.f, 0.f, 0.f);
        fa1 = fa0;
        if (arowok && kb < INF) {
            const float4* p = (const float4*)(x + (size_t)gr * INF + kb);
            fa0 = p[0]; fa1 = p[1];
        }
    };
    auto loadB = [&](int kk) {
        int kb = kk * 32 + bh * 16;
        fb0 = make_uint4(0, 0, 0, 0);
        fb1 = fb0;
        if (kb < INF) {
            const uint4* p = (const uint4*)(wTv + (size_t)brow * INF + kb);
            fb0 = p[0]; fb1 = p[1];
        }
    };
    auto stage = [&]() {
        ushort4 u0, u1;
        u0.x = f2bf(fa0.x); u0.y = f2bf(fa0.y); u0.z = f2bf(fa0.z); u0.w = f2bf(fa0.w);
        u1.x = f2bf(fa1.x); u1.y = f2bf(fa1.y); u1.z = f2bf(fa1.z); u1.w = f2bf(fa1.w);
        *(ushort4*)&lds_a[arow * LDT + aq * 8] = u0;
        *(ushort4*)&lds_a[arow * LDT + aq * 8 + 4] = u1;
        *(uint4*)&lds_b[brow * LDT + bh * 16] = fb0;
        *(uint4*)&lds_b[brow * LDT + bh * 16 + 8] = fb1;
    };

    loadA(0); loadB(0);
    for (int kk = 0; kk < KT; kk++) {
        stage();
        __syncthreads();
        if (kk + 1 < KT) { loadA(kk + 1); loadB(kk + 1); }  // overlap with MFMA below
        short8 af[2], bfr[4];
        #pragma unroll
        for (int i = 0; i < 2; i++)
            af[i] = *(const short8*)&lds_a[(wm * 32 + i * 16 + lm) * LDT + lq * 8];
        #pragma unroll
        for (int j = 0; j < 4; j++)
            bfr[j] = *(const short8*)&lds_b[(wn * 64 + j * 16 + lm) * LDT + lq * 8];
        #pragma unroll
        for (int i = 0; i < 2; i++)
            #pragma unroll
            for (int j = 0; j < 4; j++)
                acc[i][j] = __builtin_amdgcn_mfma_f32_16x16x32_bf16(af[i], bfr[j], acc[i][j], 0, 0, 0);
        __syncthreads();
    }
    // epilogue: C row=(lane>>4)*4+reg, col=lane&15  [m89-verified layout]
    #pragma unroll
    for (int i = 0; i < 2; i++) {
        int lr = wm * 32 + i * 16 + lq * 4;
        #pragma unroll
        for (int j = 0; j < 4; j++) {
            int c = wn * 64 + j * 16 + lm;
            float bv = bias[c];
            #pragma unroll
            for (int u = 0; u < 4; u++) {
                int grow = blockIdx.x * 64 + lr + u;
                if (grow < NN) {
                    float o = fmaxf(acc[i][j][u] + bv, 0.f);
                    hout[((size_t)(v * NN + grow)) * DD + c] = f2bf(o);
                }
            }
        }
    }
}

// ---------- xw GEMM: xw[r] = h @ W_r  (bf16 in, bf16 out, K=128) ----------
__global__ __launch_bounds__(256) void xw_gemm(
    const unsigned short* __restrict__ h, const unsigned short* __restrict__ wTrel,
    unsigned short* __restrict__ xw) {
    __shared__ unsigned short lds_a[128 * LDT];
    __shared__ unsigned short lds_b[128 * LDT];
    int r = blockIdx.y;
    const unsigned short* wTr = wTrel + (size_t)r * DD * DD;
    int t = threadIdx.x;
    int sr = t >> 1, sh = t & 1;
    int grow = blockIdx.x * 128 + sr;
    int grc = (grow < NTT) ? grow : (NTT - 1);  // clamp; epilogue guards
    int lane = t & 63, wid = t >> 6;
    int wm = wid >> 1, wn = wid & 1;
    int lm = lane & 15, lq = lane >> 4;

    f32x4 acc[4][4];
    #pragma unroll
    for (int i = 0; i < 4; i++)
        #pragma unroll
        for (int j = 0; j < 4; j++) {
            acc[i][j][0] = 0.f; acc[i][j][1] = 0.f; acc[i][j][2] = 0.f; acc[i][j][3] = 0.f;
        }

    #pragma unroll
    for (int kk = 0; kk < 4; kk++) {
        int k0 = kk * 32 + sh * 16;
        const uint4* asrc = (const uint4*)(h + (size_t)grc * DD + k0);
        *(uint4*)&lds_a[sr * LDT + sh * 16] = asrc[0];
        *(uint4*)&lds_a[sr * LDT + sh * 16 + 8] = asrc[1];
        const uint4* bsrc = (const uint4*)(wTr + (size_t)sr * DD + k0);
        *(uint4*)&lds_b[sr * LDT + sh * 16] = bsrc[0];
        *(uint4*)&lds_b[sr * LDT + sh * 16 + 8] = bsrc[1];
        __syncthreads();
        short8 af[4], bfr[4];
        #pragma unroll
        for (int i = 0; i < 4; i++)
            af[i] = *(const short8*)&lds_a[(wm * 64 + i * 16 + lm) * LDT + lq * 8];
        #pragma unroll
        for (int j = 0; j < 4; j++)
            bfr[j] = *(const short8*)&lds_b[(wn * 64 + j * 16 + lm) * LDT + lq * 8];
        #pragma unroll
        for (int i = 0; i < 4; i++)
            #pragma unroll
            for (int j = 0; j < 4; j++)
                acc[i][j] = __builtin_amdgcn_mfma_f32_16x16x32_bf16(af[i], bfr[j], acc[i][j], 0, 0, 0);
        __syncthreads();
    }
    #pragma unroll
    for (int i = 0; i < 4; i++) {
        int lr = wm * 64 + i * 16 + lq * 4;
        #pragma unroll
        for (int j = 0; j < 4; j++) {
            int c = wn * 64 + j * 16 + lm;
            #pragma unroll
            for (int u = 0; u < 4; u++) {
                int g2 = blockIdx.x * 128 + lr + u;
                if (g2 < NTT)
                    xw[((size_t)r * NTT + g2) * DD + c] = f2bf(acc[i][j][u]);
            }
        }
    }
}

// ---------- per-(relation,node) attention scalars ----------
__global__ void qk_nodes(const unsigned short* __restrict__ h, const float* __restrict__ qvec,
                         const float* __restrict__ kvec, float* __restrict__ qn,
                         float* __restrict__ kn) {
    int wid = threadIdx.x >> 6, lane = threadIdx.x & 63;
    int node = blockIdx.x * 4 + wid;
    if (node >= NTT) return;
    unsigned int u = *(const unsigned int*)(h + (size_t)node * DD + lane * 2);
    float h0 = bf2f(u & 0xffff), h1 = bf2f(u >> 16);
    #pragma unroll
    for (int r = 0; r < NR; r++) {
        float pq = h0 * qvec[r * DD + lane * 2] + h1 * qvec[r * DD + lane * 2 + 1];
        float pk = h0 * kvec[r * DD + lane * 2] + h1 * kvec[r * DD + lane * 2 + 1];
        #pragma unroll
        for (int off = 32; off; off >>= 1) {
            pq += __shfl_xor(pq, off);
            pk += __shfl_xor(pk, off);
        }
        if (lane == 0) {
            qn[r * NTT + node] = pq;
            kn[r * NTT + node] = pk;
        }
    }
}

// ---------- CSR build ----------
__global__ void hist(const int* __restrict__ dst, int* __restrict__ indeg) {
    int e = blockIdx.x * 256 + threadIdx.x;
    if (e < NE) atomicAdd(&indeg[dst[e]], 1);
}

__global__ __launch_bounds__(1024) void scan_indeg(const int* __restrict__ indeg,
                                                   int* __restrict__ start) {
    int t = threadIdx.x;
    const int per = (NTT + 1023) / 1024;  // 59
    int base = t * per;
    int s = 0;
    for (int i = 0; i < per; i++) {
        int idx = base + i;
        if (idx < NTT) s += indeg[idx];
    }
    int lane = t & 63, wid = t >> 6;
    __shared__ int wsum[16];
    int v = s;
    #pragma unroll
    for (int off = 1; off < 64; off <<= 1) {
        int u = __shfl_up(v, off);
        if (lane >= off) v += u;
    }
    if (lane == 63) wsum[wid] = v;
    __syncthreads();
    if (t < 16) {
        int w = wsum[t];
        #pragma unroll
        for (int off = 1; off < 16; off <<= 1) {
            int u = __shfl_up(w, off);
            if (t >= off) w += u;
        }
        wsum[t] = w;
    }
    __syncthreads();
    int excl = (v - s) + (wid ? wsum[wid - 1] : 0);
    int run = excl;
    for (int i = 0; i < per; i++) {
        int idx = base + i;
        if (idx < NTT) {
            start[idx] = run;
            run += indeg[idx];
        }
    }
    if (t == 1023) start[NTT] = run;
}

// scatter + per-edge attention weight (edge-parallel: hides qn/kn gather latency)
__global__ void scatter2(const int* __restrict__ dst, const int* __restrict__ src,
                         const int* __restrict__ typ, const int* __restrict__ start,
                         int* __restrict__ cursor, const float* __restrict__ qn,
                         const float* __restrict__ kn, unsigned int* __restrict__ packed,
                         float* __restrict__ wl) {
    int e = blockIdx.x * 256 + threadIdx.x;
    if (e >= NE) return;
    int d = dst[e], ss = src[e], tt = typ[e];
    float al = qn[tt * NTT + d] + kn[tt * NTT + ss];
    al = (al > 0.f) ? al : 0.2f * al;   // leaky_relu
    float w = __expf(al);               // softmax shift-invariance: no segment_max
    int pos = atomicAdd(&cursor[d], 1);
    int idx = start[d] + pos;
    packed[idx] = (unsigned)ss | ((unsigned)tt << 16);  // NTT<2^16, R<2^3
    wl[idx] = w;
}

// ---------- aggregation: one wave per dst node ----------
// Segment ids+weights loaded in ONE coalesced 64-wide load, broadcast by shfl;
// only the xw row gather remains in the loop (independent across iters -> MLP).
__global__ void aggregate(const unsigned int* __restrict__ packed, const float* __restrict__ wl,
                          const int* __restrict__ start, const unsigned short* __restrict__ xw,
                          const float* __restrict__ conv_bias, float* __restrict__ h2) {
    int wid = threadIdx.x >> 6, lane = threadIdx.x & 63;
    int node = blockIdx.x * 4 + wid;
    if (node >= NTT) return;
    int s0 = start[node], s1 = start[node + 1];
    float a0 = 0.f, a1 = 0.f, denom = 0.f;
    for (int base = s0; base < s1; base += 64) {
        int cnt = min(64, s1 - base);
        unsigned pk = 0;
        float wv = 0.f;
        if (lane < cnt) {
            pk = packed[base + lane];
            wv = wl[base + lane];
        }
        denom += wv;
        for (int i = 0; i < cnt; i++) {
            unsigned sp = __shfl(pk, i);
            float sw = __shfl(wv, i);
            unsigned ss = sp & 0xFFFFu;
            unsigned tt = sp >> 16;
            unsigned u = *(const unsigned int*)(xw + ((size_t)tt * NTT + ss) * DD + lane * 2);
            a0 += sw * bf2f(u & 0xffff);
            a1 += sw * bf2f(u >> 16);
        }
    }
    #pragma unroll
    for (int off = 32; off; off >>= 1) denom += __shfl_xor(denom, off);
    float rdenom = 1.f / (denom + 1e-16f);
    float2 o;
    o.x = fmaxf(a0 * rdenom + conv_bias[lane * 2], 0.f);
    o.y = fmaxf(a1 * rdenom + conv_bias[lane * 2 + 1], 0.f);
    *(float2*)&h2[(size_t)node * DD + lane * 2] = o;
}

// ---------- final linear: one wave per sample node ----------
__global__ void final_linear(const float* __restrict__ h2, const float* __restrict__ w_int,
                             const float* __restrict__ b_int, float* __restrict__ out) {
    int wid = threadIdx.x >> 6, lane = threadIdx.x & 63;
    int node = blockIdx.x * 4 + wid;
    if (node >= NN) return;
    float acc[NL] = {0.f, 0.f, 0.f, 0.f, 0.f};
    for (int j = lane; j < NV * DD; j += 64) {
        int v = j >> 7, d = j & 127;
        float f = h2[((size_t)(v * NN + node)) * DD + d];
        #pragma unroll
        for (int c = 0; c < NL; c++) acc[c] += f * w_int[j * NL + c];
    }
    #pragma unroll
    for (int c = 0; c < NL; c++) {
        float s = acc[c];
        #pragma unroll
        for (int off = 32; off; off >>= 1) s += __shfl_xor(s, off);
        if (lane == 0) out[(size_t)node * NL + c] = s + b_int[c];
    }
}

extern "C" void kernel_launch(void* const* d_in, const int* in_sizes, int n_in, void* d_out,
                              int out_size, void* d_ws, size_t ws_size, hipStream_t stream) {
    (void)in_sizes; (void)n_in; (void)out_size; (void)ws_size;
    const float* x0 = (const float*)d_in[0];
    const float* w0 = (const float*)d_in[1];
    const float* b0 = (const float*)d_in[2];
    const float* x1 = (const float*)d_in[3];
    const float* w1 = (const float*)d_in[4];
    const float* b1 = (const float*)d_in[5];
    const float* x2 = (const float*)d_in[6];
    const float* w2 = (const float*)d_in[7];
    const float* b2 = (const float*)d_in[8];
    const int* esrc = (const int*)d_in[9];
    const int* edst = (const int*)d_in[10];
    const int* etype = (const int*)d_in[11];
    const float* basis = (const float*)d_in[12];
    const float* comp = (const float*)d_in[13];
    const float* att_q = (const float*)d_in[14];
    const float* att_k = (const float*)d_in[15];
    const float* conv_bias = (const float*)d_in[16];
    const float* w_int = (const float*)d_in[17];
    const float* b_int = (const float*)d_in[18];

    char* ws = (char*)d_ws;
    size_t off = 0;
    auto alloc = [&](size_t bytes) -> void* {
        void* p = ws + off;
        off += bytes;
        off = (off + 255) & ~(size_t)255;
        return p;
    };
    unsigned short* h = (unsigned short*)alloc((size_t)NTT * DD * 2);
    unsigned short* xw = (unsigned short*)alloc((size_t)NR * NTT * DD * 2);
    float* qn = (float*)alloc((size_t)NR * NTT * 4);
    float* kn = (float*)alloc((size_t)NR * NTT * 4);
    unsigned short* wT = (unsigned short*)alloc((size_t)NV * DD * INF * 2);
    unsigned short* wTrel = (unsigned short*)alloc((size_t)NR * DD * DD * 2);
    float* qvec = (float*)alloc((size_t)NR * DD * 4);
    float* kvec = (float*)alloc((size_t)NR * DD * 4);
    int* indeg = (int*)alloc((size_t)NTT * 4);
    int* cursor = (int*)alloc((size_t)NTT * 4);
    int* startp = (int*)alloc((size_t)(NTT + 1) * 4);
    unsigned int* packed = (unsigned int*)alloc((size_t)NE * 4);
    float* wl = (float*)alloc((size_t)NE * 4);
    float* h2 = (float*)alloc((size_t)NTT * DD * 4);

    prep_wT<<<(NV * DD * INF + 255) / 256, 256, 0, stream>>>(w0, w1, w2, wT);
    prep_wrel<<<(NR * DD * DD + 255) / 256, 256, 0, stream>>>(basis, comp, wTrel);
    prep_qkvec<<<(2 * NR * DD + 255) / 256, 256, 0, stream>>>(basis, comp, att_q, att_k, qvec, kvec);
    zero2<<<(NTT + 255) / 256, 256, 0, stream>>>(indeg, cursor);

    proj_gemm<<<dim3((NN + 63) / 64, NV), 256, 0, stream>>>(x0, x1, x2, b0, b1, b2, wT, h);
    qk_nodes<<<(NTT + 3) / 4, 256, 0, stream>>>(h, qvec, kvec, qn, kn);
    xw_gemm<<<dim3((NTT + 127) / 128, NR), 256, 0, stream>>>(h, wTrel, xw);

    hist<<<(NE + 255) / 256, 256, 0, stream>>>(edst, indeg);
    scan_indeg<<<1, 1024, 0, stream>>>(indeg, startp);
    scatter2<<<(NE + 255) / 256, 256, 0, stream>>>(edst, esrc, etype, startp, cursor, qn, kn,
                                                   packed, wl);

    aggregate<<<(NTT + 3) / 4, 256, 0, stream>>>(packed, wl, startp, xw, conv_bias, h2);
    final_linear<<<(NN + 3) / 4, 256, 0, stream>>>(h2, w_int, b_int, (float*)d_out);
}